// Round 1
// baseline (853.925 us; speedup 1.0000x reference)
//
#include <hip/hip_runtime.h>

// ---------------- problem constants ----------------
// B=32, T=32, F=64, H=256, N=1024, A=64, C=192, M=256
// out: hs [32,256,32] (262144 floats) then outs [32,10,32] (10240 floats)

// ---------------- workspace (float offsets) ----------------
#define WS_G0T   0         // [320][256]  (Wh0^T rows 0..255, Wi0^T rows 256..319)
#define WS_G1T   81920     // [320][256]
#define WS_WH2T  163840    // [256][256]
#define WS_WI2T  229376    // [64][256]
#define WS_WQT   245760    // [256][256]
#define WS_CCT   311296    // [320][192]  (Wch^T rows 0..255, Wci^T rows 256..319)
#define WS_WMT   372736    // 3 x [256][256]
#define WS_ADDRT 569344    // [64][1024]
#define WS_FLOATS 634880

// ---------------- LDS layout (float offsets) ----------------
#define SH_HX   0      // [320]: h 0..255, x 256..319
#define SH_Q    320    // [512]: q half0, half1
#define SH_RD   832    // [256]: reading
#define SH_G01  1088   // [1024]: gate0 h0,h1, gate1 h0,h1
#define SH_GI2  2112   // [256]
#define SH_GH2  2368   // [512]: halves
#define SH_GM   2880   // [768]: (A: cand halves at 0..191,384..575) (D: gm half0 x3)
#define SH_D    3648   // [32]
#define SH_G    3680   // [32]
#define SH_RED  3712   // [16]
#define SH_RED2 3728   // [16]
#define SH_MISC 3744   // [8]: [0]=beta
#define SH_B10  3752   // [16]
#define SH_PART 3768   // [1024]: q_full / reading_a partials / gm half1 x3
#define SH_CAND 4792   // ushort[32*192] = 3072 floats
#define SH_W    7864   // [32][1024] w history
#define SMEM_FLOATS 40632
#define SMEM_BYTES (SMEM_FLOATS*4)

#define WRED(v) { v += __shfl_xor(v,32); v += __shfl_xor(v,16); v += __shfl_xor(v,8); \
                  v += __shfl_xor(v,4);  v += __shfl_xor(v,2);  v += __shfl_xor(v,1); }

__device__ __forceinline__ float bf2f(unsigned short h) {
  return __uint_as_float(((unsigned int)h) << 16);
}
__device__ __forceinline__ unsigned short f2bf(float x) {
  unsigned int u = __float_as_uint(x);
  unsigned int r = (u + 0x7FFFu + ((u >> 16) & 1u)) >> 16;
  return (unsigned short)r;
}

// y[o..o+3] = sum_k coef[k] * WT[k*ldm + o]   (WT,coef pre-offset by caller)
__device__ __forceinline__ void mv_unit(const float* __restrict__ WT, const int ldm,
    const float* __restrict__ coef, const int klen,
    float* __restrict__ dst, const int outlen, const int ln)
{
  const int o = ln * 4;
  if (o >= outlen) return;
  const float* wp = WT + o;
  float ax = 0.f, ay = 0.f, az = 0.f, aw = 0.f;
  #pragma unroll 4
  for (int k = 0; k < klen; k += 4) {
    const float4 c = *(const float4*)(coef + k);
    const float4 w0 = *(const float4*)(wp);
    const float4 w1 = *(const float4*)(wp + ldm);
    const float4 w2 = *(const float4*)(wp + 2 * ldm);
    const float4 w3 = *(const float4*)(wp + 3 * ldm);
    wp += 4 * ldm;
    ax = fmaf(c.x, w0.x, ax); ay = fmaf(c.x, w0.y, ay); az = fmaf(c.x, w0.z, az); aw = fmaf(c.x, w0.w, aw);
    ax = fmaf(c.y, w1.x, ax); ay = fmaf(c.y, w1.y, ay); az = fmaf(c.y, w1.z, az); aw = fmaf(c.y, w1.w, aw);
    ax = fmaf(c.z, w2.x, ax); ay = fmaf(c.z, w2.y, ay); az = fmaf(c.z, w2.z, az); aw = fmaf(c.z, w2.w, aw);
    ax = fmaf(c.w, w3.x, ax); ay = fmaf(c.w, w3.y, ay); az = fmaf(c.w, w3.z, az); aw = fmaf(c.w, w3.w, aw);
  }
  *(float4*)(dst + o) = make_float4(ax, ay, az, aw);
}

__device__ __forceinline__ void sim_unit(const float* __restrict__ addrT,
    const float* __restrict__ qf, const float* __restrict__ whist,
    const float* __restrict__ dv, const int t, const float beta,
    float* __restrict__ wout, const int nb, const int ln)
{
  const int o = nb + ln * 4;
  float ax = 0.f, ay = 0.f, az = 0.f, aw = 0.f;
  const float* ap = addrT + o;
  #pragma unroll 4
  for (int a = 0; a < 64; a += 4) {
    const float4 q4 = *(const float4*)(qf + a);
    const float4 w0 = *(const float4*)(ap + (a + 0) * 1024);
    const float4 w1 = *(const float4*)(ap + (a + 1) * 1024);
    const float4 w2 = *(const float4*)(ap + (a + 2) * 1024);
    const float4 w3 = *(const float4*)(ap + (a + 3) * 1024);
    ax = fmaf(q4.x, w0.x, ax); ay = fmaf(q4.x, w0.y, ay); az = fmaf(q4.x, w0.z, az); aw = fmaf(q4.x, w0.w, aw);
    ax = fmaf(q4.y, w1.x, ax); ay = fmaf(q4.y, w1.y, ay); az = fmaf(q4.y, w1.z, az); aw = fmaf(q4.y, w1.w, aw);
    ax = fmaf(q4.z, w2.x, ax); ay = fmaf(q4.z, w2.y, ay); az = fmaf(q4.z, w2.z, az); aw = fmaf(q4.z, w2.w, aw);
    ax = fmaf(q4.w, w3.x, ax); ay = fmaf(q4.w, w3.y, ay); az = fmaf(q4.w, w3.z, az); aw = fmaf(q4.w, w3.w, aw);
  }
  for (int s = 0; s < t; ++s) {
    const float d2 = dv[s];
    const float4 w4 = *(const float4*)(whist + s * 1024 + o);
    ax = fmaf(d2, w4.x, ax); ay = fmaf(d2, w4.y, ay); az = fmaf(d2, w4.z, az); aw = fmaf(d2, w4.w, aw);
  }
  *(float4*)(wout + o) = make_float4(beta * ax, beta * ay, beta * az, beta * aw);
}

__device__ __forceinline__ void out_lse(const float* __restrict__ b10,
    float* __restrict__ out, const int t_out, const int bb, const int ln)
{
  float v = (ln < 10) ? b10[ln] : -1e30f;
  float m = v;
  m = fmaxf(m, __shfl_xor(m, 8, 16));
  m = fmaxf(m, __shfl_xor(m, 4, 16));
  m = fmaxf(m, __shfl_xor(m, 2, 16));
  m = fmaxf(m, __shfl_xor(m, 1, 16));
  float e = (ln < 10) ? expf(v - m) : 0.f;
  float s = e;
  s += __shfl_xor(s, 8, 16);
  s += __shfl_xor(s, 4, 16);
  s += __shfl_xor(s, 2, 16);
  s += __shfl_xor(s, 1, 16);
  if (ln < 10) out[262144 + t_out * 320 + ln * 32 + bb] = v - m - logf(s);
}

// ---------------- transpose/pack pre-kernel ----------------
__global__ void pack_transpose(const float* __restrict__ Wi, const float* __restrict__ Wh,
                               const float* __restrict__ Wm, const float* __restrict__ Wq,
                               const float* __restrict__ Wch, const float* __restrict__ Wci,
                               const float* __restrict__ maddr, float* __restrict__ ws)
{
  __shared__ float tile[64][65];
  const int b2 = blockIdx.x;
  const float* src; float* dst; int K, ro, ld, tl;
  if      (b2 < 16)  { src = Wh;          K = 256; dst = ws + WS_G0T;  ro = 0;   ld = 256;  tl = b2; }
  else if (b2 < 20)  { src = Wi;          K = 64;  dst = ws + WS_G0T;  ro = 256; ld = 256;  tl = b2 - 16; }
  else if (b2 < 36)  { src = Wh + 65536;  K = 256; dst = ws + WS_G1T;  ro = 0;   ld = 256;  tl = b2 - 20; }
  else if (b2 < 40)  { src = Wi + 16384;  K = 64;  dst = ws + WS_G1T;  ro = 256; ld = 256;  tl = b2 - 36; }
  else if (b2 < 56)  { src = Wh + 131072; K = 256; dst = ws + WS_WH2T; ro = 0;   ld = 256;  tl = b2 - 40; }
  else if (b2 < 60)  { src = Wi + 32768;  K = 64;  dst = ws + WS_WI2T; ro = 0;   ld = 256;  tl = b2 - 56; }
  else if (b2 < 76)  { src = Wq;          K = 256; dst = ws + WS_WQT;  ro = 0;   ld = 256;  tl = b2 - 60; }
  else if (b2 < 88)  { src = Wch;         K = 256; dst = ws + WS_CCT;  ro = 0;   ld = 192;  tl = b2 - 76; }
  else if (b2 < 91)  { src = Wci;         K = 64;  dst = ws + WS_CCT;  ro = 256; ld = 192;  tl = b2 - 88; }
  else if (b2 < 107) { src = Wm;          K = 256; dst = ws + WS_WMT;           ro = 0; ld = 256; tl = b2 - 91; }
  else if (b2 < 123) { src = Wm + 65536;  K = 256; dst = ws + WS_WMT + 65536;   ro = 0; ld = 256; tl = b2 - 107; }
  else if (b2 < 139) { src = Wm + 131072; K = 256; dst = ws + WS_WMT + 131072;  ro = 0; ld = 256; tl = b2 - 123; }
  else               { src = maddr;       K = 64;  dst = ws + WS_ADDRT; ro = 0; ld = 1024; tl = b2 - 139; }
  const int tiles_k = K >> 6;
  const int tr = tl / tiles_k, tk = tl % tiles_k;
  const int c = threadIdx.x & 63, r4 = threadIdx.x >> 6;
  #pragma unroll 4
  for (int it = 0; it < 16; ++it) {
    const int r = it * 4 + r4;
    tile[r][c] = src[(size_t)(tr * 64 + r) * K + tk * 64 + c];
  }
  __syncthreads();
  #pragma unroll 4
  for (int it = 0; it < 16; ++it) {
    const int rr = it * 4 + r4;
    dst[(size_t)(ro + tk * 64 + rr) * ld + tr * 64 + c] = tile[c][rr];
  }
}

// ---------------- main persistent per-batch kernel ----------------
__global__ __launch_bounds__(1024, 1) void dntm_step(
    const float* __restrict__ batch, const float* __restrict__ bi,
    const float* __restrict__ bh, const float* __restrict__ bm,
    const float* __restrict__ Wo, const float* __restrict__ bo,
    const float* __restrict__ maddr, const float* __restrict__ bq,
    const float* __restrict__ usharp, const float* __restrict__ ws,
    float* __restrict__ out)
{
  extern __shared__ float sm[];
  float* hx = sm + SH_HX;
  float* shw = sm + SH_W;
  unsigned short* candh = (unsigned short*)(sm + SH_CAND);
  const int tid = threadIdx.x, ln = tid & 63, wv = tid >> 6;
  const int bb = blockIdx.x;

  // init: h=0, load x_0
  if (tid < 256) hx[tid] = 0.f;
  if (tid >= 256 && tid < 320) {
    const int f = tid - 256, idx = f * 32 + bb;
    hx[tid] = batch[(idx >> 6) * 2048 + (idx & 63)];
  }
  __syncthreads();

  for (int t = 0; t < 32; ++t) {
    // ---- Phase A: all h/x-dependent matvecs (k-split halves for SIMD balance) ----
    switch (wv) {
      case 0:  mv_unit(ws + WS_G0T,             256, hx,       160, sm + SH_G01,       256, ln); break;
      case 1:  mv_unit(ws + WS_G0T + 160 * 256, 256, hx + 160, 160, sm + SH_G01 + 256, 256, ln); break;
      case 2:  mv_unit(ws + WS_G1T,             256, hx,       160, sm + SH_G01 + 512, 256, ln); break;
      case 3:  mv_unit(ws + WS_G1T + 160 * 256, 256, hx + 160, 160, sm + SH_G01 + 768, 256, ln); break;
      case 4:  mv_unit(ws + WS_CCT,             192, hx,       160, sm + SH_GM,        192, ln); break;
      case 5:  mv_unit(ws + WS_CCT + 160 * 192, 192, hx + 160, 160, sm + SH_GM + 384,  192, ln); break;
      case 6:  mv_unit(ws + WS_WH2T,            256, hx,       128, sm + SH_GH2,       256, ln); break;
      case 7:  mv_unit(ws + WS_WH2T + 128 * 256,256, hx + 128, 128, sm + SH_GH2 + 256, 256, ln); break;
      case 8:  mv_unit(ws + WS_WI2T,            256, hx + 256,  64, sm + SH_GI2,       256, ln); break;
      case 9:  mv_unit(ws + WS_WQT + 128 * 256, 256, hx + 128, 128, sm + SH_Q + 256,   256, ln); break;
      case 10: mv_unit(ws + WS_WQT,             256, hx,       128, sm + SH_Q,         256, ln); break;
      case 11: { // beta = softplus(u.h) + 1
        const float4 h4 = *(const float4*)&hx[ln * 4];
        const float4 u4 = *(const float4*)&usharp[ln * 4];
        float v = u4.x * h4.x + u4.y * h4.y + u4.z * h4.z + u4.w * h4.w;
        WRED(v);
        if (ln == 0) sm[SH_MISC] = fmaxf(v, 0.f) + log1pf(expf(-fabsf(v))) + 1.f;
      } break;
      case 15: if (t > 0) { // logits for out[t-1] (h == h_new of step t-1)
        const float4 h4 = *(const float4*)&hx[ln * 4];
        for (int j = 0; j < 10; ++j) {
          const float4 wo = *(const float4*)&Wo[j * 256 + ln * 4];
          float v = wo.x * h4.x + wo.y * h4.y + wo.z * h4.z + wo.w * h4.w;
          WRED(v);
          if (ln == 0) sm[SH_B10 + j] = v + bo[j];
        }
      } break;
      default: break;
    }
    __syncthreads();

    // ---- Phase B1: d[s]=cand_s.q_c ; q_full -> part ; cand combine ; out[t-1] lse ----
    if (wv < 8) {
      const float qc0 = sm[SH_Q + 64  + ln] + sm[SH_Q + 320 + ln] + bq[64  + ln];
      const float qc1 = sm[SH_Q + 128 + ln] + sm[SH_Q + 384 + ln] + bq[128 + ln];
      const float qc2 = sm[SH_Q + 192 + ln] + sm[SH_Q + 448 + ln] + bq[192 + ln];
      for (int s = wv; s < t; s += 8) {
        float a2 = bf2f(candh[s * 192 + ln]) * qc0
                 + bf2f(candh[s * 192 + 64 + ln]) * qc1
                 + bf2f(candh[s * 192 + 128 + ln]) * qc2;
        WRED(a2);
        if (ln == 0) sm[SH_D + s] = a2;
      }
    } else if (wv < 12) {
      const int m2 = (wv - 8) * 64 + ln;
      sm[SH_PART + m2] = sm[SH_Q + m2] + sm[SH_Q + 256 + m2] + bq[m2];
    } else if (wv == 12) {
      for (int c = ln; c < 192; c += 64) {
        const float v3 = fmaxf(sm[SH_GM + c] + sm[SH_GM + 384 + c], 0.f);
        candh[t * 192 + c] = f2bf(v3);
      }
    } else if (wv == 13) {
      if (t > 0) out_lse(sm + SH_B10, out, t - 1, bb, ln);
    }
    __syncthreads();

    // ---- Phase B2: sim -> beta*sim into w_hist[t] ----
    if (wv < 4)
      sim_unit(ws + WS_ADDRT, sm + SH_PART, shw, sm + SH_D, t, sm[SH_MISC],
               shw + t * 1024, wv * 256, ln);
    __syncthreads();

    // ---- softmax over n (1024 threads = 1024 n) ----
    {
      const float v = shw[t * 1024 + tid];
      float mx = v;
      mx = fmaxf(mx, __shfl_xor(mx, 32)); mx = fmaxf(mx, __shfl_xor(mx, 16));
      mx = fmaxf(mx, __shfl_xor(mx, 8));  mx = fmaxf(mx, __shfl_xor(mx, 4));
      mx = fmaxf(mx, __shfl_xor(mx, 2));  mx = fmaxf(mx, __shfl_xor(mx, 1));
      if (ln == 0) sm[SH_RED + wv] = mx;
    }
    __syncthreads();
    {
      float gmx = sm[SH_RED];
      #pragma unroll
      for (int i = 1; i < 16; ++i) gmx = fmaxf(gmx, sm[SH_RED + i]);
      const float e = expf(shw[t * 1024 + tid] - gmx);
      shw[t * 1024 + tid] = e;
      float s2 = e; WRED(s2);
      if (ln == 0) sm[SH_RED2 + wv] = s2;
    }
    __syncthreads();
    {
      float tot = 0.f;
      #pragma unroll
      for (int i = 0; i < 16; ++i) tot += sm[SH_RED2 + i];
      shw[t * 1024 + tid] = shw[t * 1024 + tid] / tot;
    }
    __syncthreads();

    // ---- Phase C1: reading_a partials (per-wave n-chunk) + g[s] = w_s.w_t ----
    {
      const float* ap = maddr + (wv * 64) * 64 + ln;
      const float* wr = shw + t * 1024 + wv * 64;
      float acc = 0.f;
      #pragma unroll 8
      for (int i = 0; i < 64; ++i) acc = fmaf(ap[i * 64], wr[i], acc);
      sm[SH_PART + wv * 64 + ln] = acc;
      for (int s = wv; s < t; s += 16) {
        float a2 = 0.f;
        #pragma unroll
        for (int k2 = 0; k2 < 16; ++k2)
          a2 = fmaf(shw[s * 1024 + ln + k2 * 64], shw[t * 1024 + ln + k2 * 64], a2);
        WRED(a2);
        if (ln == 0) sm[SH_G + s] = a2;
      }
    }
    __syncthreads();

    // ---- Phase C2: assemble reading ----
    if (tid < 64) {
      float s2 = 0.f;
      #pragma unroll
      for (int w2 = 0; w2 < 16; ++w2) s2 += sm[SH_PART + w2 * 64 + tid];
      sm[SH_RD + tid] = s2;
    } else if (tid < 256) {
      const int c = tid - 64;
      float s2 = 0.f;
      for (int s3 = 0; s3 < t; ++s3) s2 = fmaf(bf2f(candh[s3 * 192 + c]), sm[SH_G + s3], s2);
      sm[SH_RD + tid] = s2;
    }
    __syncthreads();

    // ---- Phase D: gm = Wm @ reading (k-split halves) ; prefetch x_{t+1} ----
    switch (wv) {
      case 0: mv_unit(ws + WS_WMT,                       256, sm + SH_RD,       128, sm + SH_GM,         256, ln); break;
      case 1: mv_unit(ws + WS_WMT + 128 * 256,           256, sm + SH_RD + 128, 128, sm + SH_PART,       256, ln); break;
      case 2: mv_unit(ws + WS_WMT + 65536,               256, sm + SH_RD,       128, sm + SH_GM + 256,   256, ln); break;
      case 3: mv_unit(ws + WS_WMT + 65536 + 128 * 256,   256, sm + SH_RD + 128, 128, sm + SH_PART + 256, 256, ln); break;
      case 4: mv_unit(ws + WS_WMT + 131072,              256, sm + SH_RD,       128, sm + SH_GM + 512,   256, ln); break;
      case 5: mv_unit(ws + WS_WMT + 131072 + 128 * 256,  256, sm + SH_RD + 128, 128, sm + SH_PART + 512, 256, ln); break;
      case 6: if (t < 31) {
        const int idx = ln * 32 + bb;
        hx[256 + ln] = batch[(idx >> 6) * 2048 + (t + 1) * 64 + (idx & 63)];
      } break;
      default: break;
    }
    __syncthreads();

    // ---- Phase Dc: gates, h update, hs output ----
    if (tid < 256) {
      const int hh = tid;
      const float gm0 = sm[SH_GM + hh]       + sm[SH_PART + hh]       + bm[hh];
      const float gm1 = sm[SH_GM + 256 + hh] + sm[SH_PART + 256 + hh] + bm[256 + hh];
      const float gm2 = sm[SH_GM + 512 + hh] + sm[SH_PART + 512 + hh] + bm[512 + hh];
      const float g0v = sm[SH_G01 + hh]       + sm[SH_G01 + 256 + hh] + bh[hh]       + bi[hh];
      const float g1v = sm[SH_G01 + 512 + hh] + sm[SH_G01 + 768 + hh] + bh[256 + hh] + bi[256 + hh];
      const float gh2v = sm[SH_GH2 + hh] + sm[SH_GH2 + 256 + hh] + bh[512 + hh];
      const float gi2v = sm[SH_GI2 + hh] + bi[512 + hh];
      const float r = 1.f / (1.f + expf(-(g0v + gm0)));
      const float z = 1.f / (1.f + expf(-(g1v + gm1)));
      const float nn = tanhf(gi2v + gm2 + r * gh2v);
      const float hn = (1.f - z) * nn + z * hx[hh];
      hx[hh] = hn;
      out[t * 8192 + hh * 32 + bb] = hn;
    }
    __syncthreads();
  }

  // ---- epilogue: out[31] ----
  if (wv == 0) {
    const float4 h4 = *(const float4*)&hx[ln * 4];
    for (int j = 0; j < 10; ++j) {
      const float4 wo = *(const float4*)&Wo[j * 256 + ln * 4];
      float v = wo.x * h4.x + wo.y * h4.y + wo.z * h4.z + wo.w * h4.w;
      WRED(v);
      if (ln == 0) sm[SH_B10 + j] = v + bo[j];
    }
  }
  __syncthreads();
  if (wv == 0) out_lse(sm + SH_B10, out, 31, bb, ln);
}

extern "C" void kernel_launch(void* const* d_in, const int* in_sizes, int n_in,
                              void* d_out, int out_size, void* d_ws, size_t ws_size,
                              hipStream_t stream) {
  (void)in_sizes; (void)n_in; (void)out_size; (void)ws_size;
  const float* batch = (const float*)d_in[0];
  const float* Wi    = (const float*)d_in[1];
  const float* bi    = (const float*)d_in[2];
  const float* Wh    = (const float*)d_in[3];
  const float* bh    = (const float*)d_in[4];
  const float* Wm    = (const float*)d_in[5];
  const float* bm    = (const float*)d_in[6];
  const float* Wo    = (const float*)d_in[7];
  const float* bo    = (const float*)d_in[8];
  const float* maddr = (const float*)d_in[9];
  const float* Wq    = (const float*)d_in[10];
  const float* bq    = (const float*)d_in[11];
  const float* us    = (const float*)d_in[12];
  const float* Wch   = (const float*)d_in[13];
  const float* Wci   = (const float*)d_in[14];
  float* ws  = (float*)d_ws;
  float* out = (float*)d_out;

  // allow >64KB dynamic LDS (gfx950 has 160 KiB/CU)
  hipFuncSetAttribute((const void*)dntm_step,
                      hipFuncAttributeMaxDynamicSharedMemorySize, 163840);

  pack_transpose<<<155, 256, 0, stream>>>(Wi, Wh, Wm, Wq, Wch, Wci, maddr, ws);
  dntm_step<<<32, 1024, SMEM_BYTES, stream>>>(batch, bi, bh, bm, Wo, bo, maddr,
                                              bq, us, ws, out);
}